// Round 1
// baseline (376.694 us; speedup 1.0000x reference)
//
#include <hip/hip_runtime.h>

namespace {

constexpr int B_  = 2;
constexpr int N_  = 512;
constexpr int IN_ = 512;
constexpr int M_  = 300;   // MEM
constexpr int H_  = 64;    // HID
constexpr float SLOPE_ = 0.01f;

// ---------------------------------------------------------------------------
// Generic tiled fp32 GEMM:
//   C[z][r,c] = scale_z * (sum_k A[z][r,k] * W[z][k,c]) + bias[c]
// TM=32 rows, TN=64 cols, TK=16; 128 threads; 4x4 micro-tile per thread.
// R must be a multiple of 32. K, Cc arbitrary (guarded tails).
// Zsum != nullptr -> scale_z = 1/Zsum[z]   (used for att@h with softmax denom)
// ---------------------------------------------------------------------------
__global__ __launch_bounds__(128)
void gemm_tiled(const float* __restrict__ Ab, const float* __restrict__ Wb,
                const float* __restrict__ bias, const float* __restrict__ Zsum,
                float* __restrict__ Cb, int R, int K, int Cc,
                long strA, long strW, long strC)
{
    __shared__ __align__(16) float As[16][36];  // [k][m], pad 32->36 (16B-aligned rows)
    __shared__ __align__(16) float Ws[16][64];  // [k][n]

    const int z = blockIdx.z;
    const float* A = Ab + (long)z * strA;
    const float* W = Wb + (long)z * strW;
    float*       C = Cb + (long)z * strC;

    const int t    = threadIdx.x;
    const int row0 = blockIdx.y * 32;
    const int col0 = blockIdx.x * 64;
    const int tm0  = (t >> 4) * 4;        // 0..28
    const int tn0  = (t & 15) * 4;        // 0..60

    const int arow = row0 + (t >> 2);     // 32 rows, 4 threads/row
    const int akg  = (t & 3) * 4;         // k-subgroup within TK
    const int wcol = col0 + (t & 15) * 4;
    const int wkr  = t >> 4;              // 0..7 (two passes for 16 k-rows)

    float acc[4][4] = {};

    for (int k0 = 0; k0 < K; k0 += 16) {
        // ---- stage A tile (transposed into LDS: As[k][m]) ----
        float4 av;
        if (k0 + 16 <= K) {
            av = *(const float4*)(A + (long)arow * K + k0 + akg);
        } else {
            float tv[4];
            #pragma unroll
            for (int u = 0; u < 4; ++u) {
                const int k = k0 + akg + u;
                tv[u] = (k < K) ? A[(long)arow * K + k] : 0.0f;
            }
            av = make_float4(tv[0], tv[1], tv[2], tv[3]);
        }
        As[akg + 0][t >> 2] = av.x;
        As[akg + 1][t >> 2] = av.y;
        As[akg + 2][t >> 2] = av.z;
        As[akg + 3][t >> 2] = av.w;

        // ---- stage W tile ----
        #pragma unroll
        for (int pz = 0; pz < 2; ++pz) {
            const int k  = wkr + pz * 8;
            const int gk = k0 + k;
            float4 wv = make_float4(0.f, 0.f, 0.f, 0.f);
            if (gk < K) {
                if (wcol + 3 < Cc) {
                    wv = *(const float4*)(W + (long)gk * Cc + wcol);
                } else {
                    float tv[4];
                    #pragma unroll
                    for (int u = 0; u < 4; ++u)
                        tv[u] = (wcol + u < Cc) ? W[(long)gk * Cc + wcol + u] : 0.0f;
                    wv = make_float4(tv[0], tv[1], tv[2], tv[3]);
                }
            }
            *(float4*)&Ws[k][(t & 15) * 4] = wv;
        }
        __syncthreads();

        #pragma unroll
        for (int k = 0; k < 16; ++k) {
            const float4 a4 = *(const float4*)&As[k][tm0];
            const float4 w4 = *(const float4*)&Ws[k][tn0];
            const float aa[4] = {a4.x, a4.y, a4.z, a4.w};
            const float ww[4] = {w4.x, w4.y, w4.z, w4.w};
            #pragma unroll
            for (int i = 0; i < 4; ++i)
                #pragma unroll
                for (int j = 0; j < 4; ++j)
                    acc[i][j] = fmaf(aa[i], ww[j], acc[i][j]);
        }
        __syncthreads();
    }

    const float scale = (Zsum != nullptr) ? (1.0f / Zsum[z]) : 1.0f;
    const int cbase = col0 + tn0;
    float bv[4] = {0.f, 0.f, 0.f, 0.f};
    if (bias != nullptr) {
        #pragma unroll
        for (int j = 0; j < 4; ++j)
            if (cbase + j < Cc) bv[j] = bias[cbase + j];
    }
    #pragma unroll
    for (int i = 0; i < 4; ++i) {
        const int r = row0 + tm0 + i;
        if (cbase + 3 < Cc) {
            float4 o;
            o.x = fmaf(acc[i][0], scale, bv[0]);
            o.y = fmaf(acc[i][1], scale, bv[1]);
            o.z = fmaf(acc[i][2], scale, bv[2]);
            o.w = fmaf(acc[i][3], scale, bv[3]);
            *(float4*)(C + (long)r * Cc + cbase) = o;
        } else {
            #pragma unroll
            for (int j = 0; j < 4; ++j)
                if (cbase + j < Cc)
                    C[(long)r * Cc + cbase + j] = fmaf(acc[i][j], scale, bv[j]);
        }
    }
}

// ---------------------------------------------------------------------------
// Attention numerator:
//   e[b,i,j]  = leaky_relu( sum_h relu(si[b,i,h] + sj[b,j,h]) * a2w[h] + a2b )
//   p[b,i,j]  = adj[b,i,j] * exp(e)           (mask is exact 0/1 floats)
//   Zsum[b]  += sum over tile of p            (softmax is over flat N*N!)
// Max-subtraction skipped deliberately: |e| <= O(10), exp() is exact-safe in
// fp32 and softmax(l) == exp(l)/sum(exp(l)) identically.
// Grid (N/32, N/32, B), 256 threads; each thread: 1 i x 4 j (j = jl + 8u).
// LDS stride 68 -> conflict-free b128 reads for both Si[i][h] and Sj[j][h].
// ---------------------------------------------------------------------------
__global__ __launch_bounds__(256)
void attn_p_kernel(const float* __restrict__ si, const float* __restrict__ sj,
                   const float* __restrict__ adj, const float* __restrict__ a2w,
                   const float* __restrict__ a2b, float* __restrict__ p,
                   float* __restrict__ Zsum)
{
    __shared__ __align__(16) float Si[32][68];
    __shared__ __align__(16) float Sj[32][68];

    const int b  = blockIdx.z;
    const int i0 = blockIdx.y * 32;
    const int j0 = blockIdx.x * 32;
    const int t  = threadIdx.x;

    {   // stage 32x64 tiles of si and sj (8 floats per thread each)
        const int r  = t >> 3;
        const int hc = (t & 7) * 8;
        const float* gi = si + ((long)(b * N_ + i0 + r)) * H_ + hc;
        const float* gj = sj + ((long)(b * N_ + j0 + r)) * H_ + hc;
        *(float4*)&Si[r][hc]     = *(const float4*)(gi);
        *(float4*)&Si[r][hc + 4] = *(const float4*)(gi + 4);
        *(float4*)&Sj[r][hc]     = *(const float4*)(gj);
        *(float4*)&Sj[r][hc + 4] = *(const float4*)(gj + 4);
    }
    __syncthreads();

    const int i  = t >> 3;   // 0..31
    const int jl = t & 7;    // j = j0 + jl + 8u

    float e[4] = {0.f, 0.f, 0.f, 0.f};
    #pragma unroll
    for (int h0 = 0; h0 < H_; h0 += 4) {
        const float4 a4 = *(const float4*)&Si[i][h0];
        const float w0v = a2w[h0 + 0];   // uniform -> s_load, cached
        const float w1v = a2w[h0 + 1];
        const float w2v = a2w[h0 + 2];
        const float w3v = a2w[h0 + 3];
        #pragma unroll
        for (int u = 0; u < 4; ++u) {
            const float4 b4 = *(const float4*)&Sj[jl + 8 * u][h0];
            e[u] = fmaf(fmaxf(a4.x + b4.x, 0.f), w0v, e[u]);
            e[u] = fmaf(fmaxf(a4.y + b4.y, 0.f), w1v, e[u]);
            e[u] = fmaf(fmaxf(a4.z + b4.z, 0.f), w2v, e[u]);
            e[u] = fmaf(fmaxf(a4.w + b4.w, 0.f), w3v, e[u]);
        }
    }

    const float a2bv = a2b[0];
    const long rowbase = ((long)(b * N_ + i0 + i)) * N_ + j0 + jl;
    float lsum = 0.f;
    #pragma unroll
    for (int u = 0; u < 4; ++u) {
        float ev = e[u] + a2bv;
        ev = (ev >= 0.f) ? ev : SLOPE_ * ev;
        const float m  = adj[rowbase + 8 * u];
        const float pv = m * __expf(ev);
        p[rowbase + 8 * u] = pv;
        lsum += pv;
    }

    // block-reduce lsum -> one atomic per block
    #pragma unroll
    for (int off = 32; off > 0; off >>= 1)
        lsum += __shfl_down(lsum, off, 64);
    __shared__ float red[4];
    if ((t & 63) == 0) red[t >> 6] = lsum;
    __syncthreads();
    if (t == 0)
        atomicAdd(&Zsum[b], red[0] + red[1] + red[2] + red[3]);
}

} // namespace

extern "C" void kernel_launch(void* const* d_in, const int* in_sizes, int n_in,
                              void* d_out, int out_size, void* d_ws, size_t ws_size,
                              hipStream_t stream)
{
    const float* feature = (const float*)d_in[0];
    const float* adj     = (const float*)d_in[1];
    const float* w0      = (const float*)d_in[2];
    const float* b0      = (const float*)d_in[3];
    const float* w1      = (const float*)d_in[4];
    const float* b1      = (const float*)d_in[5];
    const float* a1w     = (const float*)d_in[6];   // (600, 64) row-major
    const float* a1b     = (const float*)d_in[7];
    const float* a2w     = (const float*)d_in[8];
    const float* a2b     = (const float*)d_in[9];
    float* out = (float*)d_out;

    // workspace layout (floats): h | f1 | si | sj | p | Z   (~5.1 MB total)
    float* ws = (float*)d_ws;
    float* h  = ws;
    float* f1 = h  + (long)B_ * N_ * M_;
    float* si = f1 + (long)B_ * N_ * M_;
    float* sj = si + (long)B_ * N_ * H_;
    float* p  = sj + (long)B_ * N_ * H_;
    float* Zs = p  + (long)B_ * N_ * N_;

    const dim3 gblk(128);
    const long NN = (long)N_ * N_;
    const long NM = (long)N_ * M_;

    for (int layer = 0; layer < 2; ++layer) {
        const float* x  = (layer == 0) ? feature : f1;
        const float* wl = (layer == 0) ? w0 : w1;
        const float* bl = (layer == 0) ? b0 : b1;
        const int    K  = (layer == 0) ? IN_ : M_;
        float*       dst = (layer == 0) ? f1 : out;

        // h = x @ wl + bl                      (1024 x K) @ (K x 300)
        gemm_tiled<<<dim3(5, 32, 1), gblk, 0, stream>>>(
            x, wl, bl, nullptr, h, B_ * N_, K, M_, 0, 0, 0);
        // si = h @ a1w[:300]                   (1024 x 300) @ (300 x 64)
        gemm_tiled<<<dim3(1, 32, 1), gblk, 0, stream>>>(
            h, a1w, nullptr, nullptr, si, B_ * N_, M_, H_, 0, 0, 0);
        // sj = h @ a1w[300:] + a1b             (a1_b folded here)
        gemm_tiled<<<dim3(1, 32, 1), gblk, 0, stream>>>(
            h, a1w + (long)M_ * H_, a1b, nullptr, sj, B_ * N_, M_, H_, 0, 0, 0);

        hipMemsetAsync(Zs, 0, B_ * sizeof(float), stream);
        attn_p_kernel<<<dim3(N_ / 32, N_ / 32, B_), dim3(256), 0, stream>>>(
            si, sj, adj, a2w, a2b, p, Zs);

        // dst = (1/Z_b) * p @ h                per-batch (512x512)@(512x300)
        gemm_tiled<<<dim3(5, N_ / 32, B_), gblk, 0, stream>>>(
            p, h, nullptr, Zs, dst, N_, N_, M_, NN, NM, NM);
    }
}

// Round 2
// 259.011 us; speedup vs baseline: 1.4544x; 1.4544x over previous
//
#include <hip/hip_runtime.h>

namespace {

constexpr int B_  = 2;
constexpr int N_  = 512;
constexpr int IN_ = 512;
constexpr int M_  = 300;   // MEM
constexpr int H_  = 64;    // HID
constexpr float SLOPE_ = 0.01f;

// ---------------------------------------------------------------------------
// Split-K fp32 GEMM, 64x64 tile, 256 threads, 4x4 micro-tile, TK=16.
//   z = sel * nchunk + chunk;  sel picks batch/W-half via strides,
//   chunk picks K-range [chunk*Kc, min((chunk+1)*Kc, K)).
// Partial results atomicAdd'ed into C (must be zeroed). chunk==0 adds bias.
//   bias = (sel==0) ? bias0 : bias1   (either may be null)
// R must be a multiple of 64; Cc arbitrary (multiple of 4); Kc multiple of 16.
// ---------------------------------------------------------------------------
__global__ __launch_bounds__(256)
void gemm_splitk(const float* __restrict__ Ab, const float* __restrict__ Wb,
                 const float* __restrict__ bias0, const float* __restrict__ bias1,
                 float* __restrict__ Cb, int R, int K, int Cc, int Kc, int nchunk,
                 long strA, long strW, long strC)
{
    __shared__ __align__(16) float As[16][68];  // [k][m], stride 68: 2-way max
    __shared__ __align__(16) float Ws[16][64];  // [k][n]

    const int sel   = blockIdx.z / nchunk;
    const int chunk = blockIdx.z % nchunk;
    const float* A = Ab + (long)sel * strA;
    const float* W = Wb + (long)sel * strW;
    float*       C = Cb + (long)sel * strC;
    const float* bias = (sel == 0) ? bias0 : bias1;

    const int kstart = chunk * Kc;
    const int kend   = min(kstart + Kc, K);

    const int t    = threadIdx.x;
    const int row0 = blockIdx.y * 64;
    const int col0 = blockIdx.x * 64;
    const int tm0  = (t >> 4) * 4;        // 0..60
    const int tn0  = (t & 15) * 4;        // 0..60

    const int arow = row0 + (t >> 2);     // 64 rows, 4 threads/row
    const int akg  = (t & 3) * 4;         // k sub-offset (0,4,8,12)
    const int wk   = t >> 4;              // 0..15
    const int wc   = (t & 15) * 4;        // 0..60

    float acc[4][4] = {};

    for (int k0 = kstart; k0 < kend; k0 += 16) {
        // ---- stage A tile, transposed: As[k][m] ----
        float4 av;
        if (k0 + akg + 4 <= kend) {
            av = *(const float4*)(A + (long)arow * K + k0 + akg);
        } else {
            float tv[4];
            #pragma unroll
            for (int u = 0; u < 4; ++u) {
                const int k = k0 + akg + u;
                tv[u] = (k < kend) ? A[(long)arow * K + k] : 0.0f;
            }
            av = make_float4(tv[0], tv[1], tv[2], tv[3]);
        }
        As[akg + 0][t >> 2] = av.x;
        As[akg + 1][t >> 2] = av.y;
        As[akg + 2][t >> 2] = av.z;
        As[akg + 3][t >> 2] = av.w;

        // ---- stage W tile: Ws[k][n] ----
        {
            const int gk = k0 + wk;
            float4 wv = make_float4(0.f, 0.f, 0.f, 0.f);
            if (gk < kend && col0 + wc + 3 < Cc)
                wv = *(const float4*)(W + (long)gk * Cc + col0 + wc);
            *(float4*)&Ws[wk][wc] = wv;
        }
        __syncthreads();

        #pragma unroll
        for (int k = 0; k < 16; ++k) {
            const float4 a4 = *(const float4*)&As[k][tm0];
            const float4 w4 = *(const float4*)&Ws[k][tn0];
            const float aa[4] = {a4.x, a4.y, a4.z, a4.w};
            const float ww[4] = {w4.x, w4.y, w4.z, w4.w};
            #pragma unroll
            for (int i = 0; i < 4; ++i)
                #pragma unroll
                for (int j = 0; j < 4; ++j)
                    acc[i][j] = fmaf(aa[i], ww[j], acc[i][j]);
        }
        __syncthreads();
    }

    const int cbase = col0 + tn0;
    float bv[4] = {0.f, 0.f, 0.f, 0.f};
    if (bias != nullptr && chunk == 0) {
        #pragma unroll
        for (int j = 0; j < 4; ++j)
            if (cbase + j < Cc) bv[j] = bias[cbase + j];
    }
    #pragma unroll
    for (int i = 0; i < 4; ++i) {
        const int r = row0 + tm0 + i;
        #pragma unroll
        for (int j = 0; j < 4; ++j)
            if (cbase + j < Cc)
                atomicAdd(&C[(long)r * Cc + cbase + j], acc[i][j] + bv[j]);
    }
}

// ---------------------------------------------------------------------------
// Attention numerator:
//   e[b,i,j]  = leaky_relu( sum_h relu(si[b,i,h] + sj[b,j,h]) * a2w[h] + a2b )
//   p[b,i,j]  = adj[b,i,j] * exp(e);   Zsum[b] += sum(p)   (softmax over flat N*N)
// Max-subtraction skipped deliberately: |e| <= O(10) so exp is fp32-safe and
// softmax(l) == exp(l)/sum(exp(l)) identically.
// ---------------------------------------------------------------------------
__global__ __launch_bounds__(256)
void attn_p_kernel(const float* __restrict__ si, const float* __restrict__ sj,
                   const float* __restrict__ adj, const float* __restrict__ a2w,
                   const float* __restrict__ a2b, float* __restrict__ p,
                   float* __restrict__ Zsum)
{
    __shared__ __align__(16) float Si[32][68];
    __shared__ __align__(16) float Sj[32][68];

    const int b  = blockIdx.z;
    const int i0 = blockIdx.y * 32;
    const int j0 = blockIdx.x * 32;
    const int t  = threadIdx.x;

    {   // stage 32x64 tiles of si and sj
        const int r  = t >> 3;
        const int hc = (t & 7) * 8;
        const float* gi = si + ((long)(b * N_ + i0 + r)) * H_ + hc;
        const float* gj = sj + ((long)(b * N_ + j0 + r)) * H_ + hc;
        *(float4*)&Si[r][hc]     = *(const float4*)(gi);
        *(float4*)&Si[r][hc + 4] = *(const float4*)(gi + 4);
        *(float4*)&Sj[r][hc]     = *(const float4*)(gj);
        *(float4*)&Sj[r][hc + 4] = *(const float4*)(gj + 4);
    }
    __syncthreads();

    const int i  = t >> 3;   // 0..31
    const int jl = t & 7;    // j = j0 + jl + 8u

    float e[4] = {0.f, 0.f, 0.f, 0.f};
    #pragma unroll
    for (int h0 = 0; h0 < H_; h0 += 4) {
        const float4 a4 = *(const float4*)&Si[i][h0];
        const float w0v = a2w[h0 + 0];
        const float w1v = a2w[h0 + 1];
        const float w2v = a2w[h0 + 2];
        const float w3v = a2w[h0 + 3];
        #pragma unroll
        for (int u = 0; u < 4; ++u) {
            const float4 b4 = *(const float4*)&Sj[jl + 8 * u][h0];
            e[u] = fmaf(fmaxf(a4.x + b4.x, 0.f), w0v, e[u]);
            e[u] = fmaf(fmaxf(a4.y + b4.y, 0.f), w1v, e[u]);
            e[u] = fmaf(fmaxf(a4.z + b4.z, 0.f), w2v, e[u]);
            e[u] = fmaf(fmaxf(a4.w + b4.w, 0.f), w3v, e[u]);
        }
    }

    const float a2bv = a2b[0];
    const long rowbase = ((long)(b * N_ + i0 + i)) * N_ + j0 + jl;
    float lsum = 0.f;
    #pragma unroll
    for (int u = 0; u < 4; ++u) {
        float ev = e[u] + a2bv;
        ev = (ev >= 0.f) ? ev : SLOPE_ * ev;
        const float m  = adj[rowbase + 8 * u];
        const float pv = m * __expf(ev);
        p[rowbase + 8 * u] = pv;
        lsum += pv;
    }

    #pragma unroll
    for (int off = 32; off > 0; off >>= 1)
        lsum += __shfl_down(lsum, off, 64);
    __shared__ float red[4];
    if ((t & 63) == 0) red[t >> 6] = lsum;
    __syncthreads();
    if (t == 0)
        atomicAdd(&Zsum[b], red[0] + red[1] + red[2] + red[3]);
}

// h[b,:,:] *= 1/Z[b]  (folds softmax denominator before p@h)
__global__ __launch_bounds__(256)
void scale_h_kernel(float* __restrict__ h, const float* __restrict__ Zs)
{
    const int idx = blockIdx.x * 256 + threadIdx.x;          // one float4 each
    const int per_b = (N_ * M_) / 4;                          // 38400
    const int b = idx / per_b;
    const float s = 1.0f / Zs[b];
    float4 v = *((float4*)h + idx);
    v.x *= s; v.y *= s; v.z *= s; v.w *= s;
    *((float4*)h + idx) = v;
}

} // namespace

extern "C" void kernel_launch(void* const* d_in, const int* in_sizes, int n_in,
                              void* d_out, int out_size, void* d_ws, size_t ws_size,
                              hipStream_t stream)
{
    const float* feature = (const float*)d_in[0];
    const float* adj     = (const float*)d_in[1];
    const float* w0      = (const float*)d_in[2];
    const float* b0      = (const float*)d_in[3];
    const float* w1      = (const float*)d_in[4];
    const float* b1      = (const float*)d_in[5];
    const float* a1w     = (const float*)d_in[6];   // (600, 64) row-major
    const float* a1b     = (const float*)d_in[7];
    const float* a2w     = (const float*)d_in[8];
    const float* a2b     = (const float*)d_in[9];
    float* out = (float*)d_out;

    // ws layout (floats): f1 | h | si | sj | Zs(pad 16) | p
    float* ws = (float*)d_ws;
    float* f1 = ws;
    float* h  = f1 + (long)B_ * N_ * M_;            // +614400
    float* si = h  + (long)B_ * N_ * M_;            // +614400
    float* sj = si + (long)B_ * N_ * H_;            // +65536
    float* Zs = sj + (long)B_ * N_ * H_;            // +65536
    float* p  = Zs + 16;                            // 16B-aligned for float4

    const long NN = (long)N_ * N_;
    const long NM = (long)N_ * M_;
    const size_t zero0 = ((size_t)(2 * B_ * N_ * M_ + 2 * B_ * N_ * H_) + 16) * 4;
    const size_t zero1 = ((size_t)(B_ * N_ * M_ + 2 * B_ * N_ * H_) + 16) * 4;

    for (int layer = 0; layer < 2; ++layer) {
        const float* x  = (layer == 0) ? feature : f1;
        const float* wl = (layer == 0) ? w0 : w1;
        const float* bl = (layer == 0) ? b0 : b1;
        const int    K  = (layer == 0) ? IN_ : M_;
        float*       dst = (layer == 0) ? f1 : out;

        if (layer == 0) hipMemsetAsync(f1, 0, zero0, stream);        // f1..Zs
        else {
            hipMemsetAsync(h, 0, zero1, stream);                     // h..Zs
            hipMemsetAsync(out, 0, (size_t)B_ * N_ * M_ * 4, stream);
        }

        // h = x @ wl + bl        (1024 x K) @ (K x 300), split-K
        {
            const int Kc = (K == 512) ? 128 : 80;
            const int nch = (K + Kc - 1) / Kc;
            gemm_splitk<<<dim3(5, 16, nch), dim3(256), 0, stream>>>(
                x, wl, bl, nullptr, h, B_ * N_, K, M_, Kc, nch, 0, 0, 0);
        }
        // [si | sj] = h @ [a1w_top | a1w_bot(+a1b)]   batched via sel
        gemm_splitk<<<dim3(1, 16, 2 * 5), dim3(256), 0, stream>>>(
            h, a1w, nullptr, a1b, si, B_ * N_, M_, H_, 64, 5,
            0, (long)M_ * H_, (long)B_ * N_ * H_);

        attn_p_kernel<<<dim3(N_ / 32, N_ / 32, B_), dim3(256), 0, stream>>>(
            si, sj, adj, a2w, a2b, p, Zs);

        scale_h_kernel<<<dim3((B_ * N_ * M_) / (4 * 256)), dim3(256), 0, stream>>>(h, Zs);

        // dst = p @ h_scaled     per-batch (512x512)@(512x300), split-K
        gemm_splitk<<<dim3(5, 8, 2 * 4), dim3(256), 0, stream>>>(
            p, h, nullptr, nullptr, dst, N_, N_, M_, 128, 4, NN, NM, NM);
    }
}